// Round 1
// baseline (1063.574 us; speedup 1.0000x reference)
//
#include <hip/hip_runtime.h>

typedef _Float16 f16x8 __attribute__((ext_vector_type(8)));
typedef float f32x4 __attribute__((ext_vector_type(4)));

#define CDIM 256
#define NE 1024
#define HW 4096        // H*W
#define CHW 1048576    // C*H*W
#define OUT_COS 262144 // 16*64*256
#define N_PIX 65536

// ws layout:
//   [0, 512K)        codebook hi halves   [1024][256]
//   [512K, 1M)       codebook lo halves   [1024][256]
//   [1M, 1M+4K)      0.5*||c||^2 (fp32, accumulated in fp64)

__global__ void prep_kernel(const float* __restrict__ cb,
                            _Float16* __restrict__ hi,
                            _Float16* __restrict__ lo,
                            float* __restrict__ cb2h) {
    int code = blockIdx.x;
    int lane = threadIdx.x; // 64 threads = 1 wave
    const float* row = cb + code * CDIM;
    double s = 0.0;
    #pragma unroll
    for (int i = 0; i < 4; ++i) {
        int c = i * 64 + lane;
        float x = row[c];
        s += (double)x * (double)x;
        _Float16 h = (_Float16)x;
        float r = x - (float)h;
        hi[code * CDIM + c] = h;
        lo[code * CDIM + c] = (_Float16)r;
    }
    #pragma unroll
    for (int off = 32; off > 0; off >>= 1)
        s += __shfl_down(s, off, 64);
    if (lane == 0) cb2h[code] = (float)(0.5 * s);
}

// One block = 64 consecutive pixels (one full w-row at fixed b,h).
// 4 waves x 16 rows each. Full K=256 of A held in registers (hi+lo fp16).
// Loop 64 tiles of 16 codes; 24 MFMAs per tile (hi*hi + hi*lo + lo*hi).
__launch_bounds__(256, 2)
__global__ void argmin_kernel(const float* __restrict__ X,
                              const _Float16* __restrict__ cbhi,
                              const _Float16* __restrict__ cblo,
                              const float* __restrict__ cb2h,
                              float* __restrict__ out_idx) {
    const int wave = threadIdx.x >> 6;
    const int lane = threadIdx.x & 63;
    const int quad = lane >> 4;
    const int l15 = lane & 15;
    const int p0 = blockIdx.x * 64;

    // A-operand: lane holds row m=l15 (of this wave's 16-row tile),
    // k = quad*8 + j within each K=32 fragment.
    const int p = p0 + wave * 16 + l15;
    const int bb = p >> 12;   // batch index
    const int hw = p & 4095;  // h*64 + w
    const float* xbase = X + (size_t)bb * CHW + hw;

    f16x8 ahi[8], alo[8];
    #pragma unroll
    for (int f = 0; f < 8; ++f) {
        #pragma unroll
        for (int j = 0; j < 8; ++j) {
            int c = f * 32 + quad * 8 + j;
            float x = xbase[(size_t)c * HW];
            _Float16 h = (_Float16)x;
            ahi[f][j] = h;
            alo[f][j] = (_Float16)(x - (float)h);
        }
    }

    float bestv[4] = {3.4e38f, 3.4e38f, 3.4e38f, 3.4e38f};
    int   besti[4] = {0, 0, 0, 0};

    for (int jt = 0; jt < 64; ++jt) {
        const int n = jt * 16 + l15; // this lane's code (B row) in the tile
        const _Float16* bh_ptr = cbhi + (size_t)n * CDIM + quad * 8;
        const _Float16* bl_ptr = cblo + (size_t)n * CDIM + quad * 8;
        f16x8 bh[8], bl[8];
        #pragma unroll
        for (int f = 0; f < 8; ++f) {
            bh[f] = *(const f16x8*)(bh_ptr + f * 32);
            bl[f] = *(const f16x8*)(bl_ptr + f * 32);
        }
        f32x4 acc = {0.f, 0.f, 0.f, 0.f};
        #pragma unroll
        for (int f = 0; f < 8; ++f)
            acc = __builtin_amdgcn_mfma_f32_16x16x32_f16(ahi[f], bh[f], acc, 0, 0, 0);
        #pragma unroll
        for (int f = 0; f < 8; ++f)
            acc = __builtin_amdgcn_mfma_f32_16x16x32_f16(ahi[f], bl[f], acc, 0, 0, 0);
        #pragma unroll
        for (int f = 0; f < 8; ++f)
            acc = __builtin_amdgcn_mfma_f32_16x16x32_f16(alo[f], bh[f], acc, 0, 0, 0);

        const float c2 = cb2h[n]; // 0.5*||c||^2
        #pragma unroll
        for (int r = 0; r < 4; ++r) {
            float s = c2 - acc[r]; // argmin of ||x-c||^2 <=> argmin 0.5||c||^2 - x.c
            if (s < bestv[r]) { bestv[r] = s; besti[r] = n; }
        }
    }

    // Cross-lane min over the 16 lanes (same quad) that hold disjoint code
    // subsets for the same 4 rows. First-index tie-break to match argmin.
    #pragma unroll
    for (int r = 0; r < 4; ++r) {
        #pragma unroll
        for (int off = 8; off > 0; off >>= 1) {
            float ov = __shfl_xor(bestv[r], off, 64);
            int   oi = __shfl_xor(besti[r], off, 64);
            if (ov < bestv[r] || (ov == bestv[r] && oi < besti[r])) {
                bestv[r] = ov; besti[r] = oi;
            }
        }
        if (l15 == 0) {
            // C/D layout: reg r -> row quad*4+r of the 16-row tile
            out_idx[p0 + wave * 16 + quad * 4 + r] = (float)besti[r];
        }
    }
}

// cosine over the H axis: one block per (b,w), one thread per channel c.
__global__ void cosine_kernel(const float* __restrict__ cb,
                              const float* __restrict__ idx_z_f,
                              const float* __restrict__ idx_gt_f,
                              float* __restrict__ out_cos) {
    const int bw = blockIdx.x;        // b*64 + w
    const int c = threadIdx.x;        // 256
    const int b = bw >> 6, w = bw & 63;
    float num = 0.f, sa = 0.f, sb = 0.f;
    for (int h = 0; h < 64; ++h) {
        const int p = b * 4096 + h * 64 + w;
        const int ig = (int)idx_gt_f[p];
        const int iq = (int)idx_z_f[p];
        const float av = cb[ig * CDIM + c]; // z_q_gt element
        const float bv = cb[iq * CDIM + c]; // z_q element
        num += av * bv;
        sa += av * av;
        sb += bv * bv;
    }
    const float nx = fmaxf(sqrtf(sa), 1e-8f);
    const float ny = fmaxf(sqrtf(sb), 1e-8f);
    out_cos[bw * CDIM + c] = num / (nx * ny);
}

extern "C" void kernel_launch(void* const* d_in, const int* in_sizes, int n_in,
                              void* d_out, int out_size, void* d_ws, size_t ws_size,
                              hipStream_t stream) {
    const float* z  = (const float*)d_in[0];
    const float* gt = (const float*)d_in[1];
    const float* cb = (const float*)d_in[2];
    float* out = (float*)d_out;

    _Float16* hi = (_Float16*)d_ws;
    _Float16* lo = hi + NE * CDIM;
    float* cb2h = (float*)(lo + NE * CDIM);

    float* out_cos    = out;                      // (16,64,256)
    float* out_idx_gt = out + OUT_COS;            // (65536,1)
    float* out_idx_z  = out + OUT_COS + N_PIX;    // (65536,1)

    prep_kernel<<<NE, 64, 0, stream>>>(cb, hi, lo, cb2h);
    argmin_kernel<<<1024, 256, 0, stream>>>(z,  hi, lo, cb2h, out_idx_z);
    argmin_kernel<<<1024, 256, 0, stream>>>(gt, hi, lo, cb2h, out_idx_gt);
    cosine_kernel<<<1024, 256, 0, stream>>>(cb, out_idx_z, out_idx_gt, out_cos);
}

// Round 2
// 343.966 us; speedup vs baseline: 3.0921x; 3.0921x over previous
//
#include <hip/hip_runtime.h>

typedef _Float16 f16x8 __attribute__((ext_vector_type(8)));
typedef float f32x4 __attribute__((ext_vector_type(4)));

#define CDIM 256
#define NE 1024
#define HW 4096        // H*W
#define CHW 1048576    // C*H*W
#define OUT_COS 262144 // 16*64*256
#define N_PIX 65536
#define NT 64          // 16-code tiles in codebook

// ws layout:
//   [0, 512K)        codebook hi halves, TILED: jt*4096 + f*512 + q*128 + n*8 + r
//                    (code = jt*16+n, dim = f*32+q*8+r)
//   [512K, 1M)       codebook lo halves, same tiling
//   [1M, 1M+4K)      0.5*||c||^2 (fp32, accumulated in fp64)

__global__ void prep_kernel(const float* __restrict__ cb,
                            _Float16* __restrict__ hi,
                            _Float16* __restrict__ lo,
                            float* __restrict__ cb2h) {
    int code = blockIdx.x;
    int lane = threadIdx.x; // 64 threads = 1 wave
    int jt = code >> 4, n = code & 15;
    const float* row = cb + code * CDIM;
    double s = 0.0;
    #pragma unroll
    for (int i = 0; i < 4; ++i) {
        int c = i * 64 + lane;
        float x = row[c];
        s += (double)x * (double)x;
        _Float16 h = (_Float16)x;
        float r = x - (float)h;
        int f = c >> 5, q = (c >> 3) & 3, rr = c & 7;
        size_t off = (size_t)jt * 4096 + f * 512 + q * 128 + n * 8 + rr;
        hi[off] = h;
        lo[off] = (_Float16)r;
    }
    #pragma unroll
    for (int off = 32; off > 0; off >>= 1)
        s += __shfl_down(s, off, 64);
    if (lane == 0) cb2h[code] = (float)(0.5 * s);
}

__device__ __forceinline__ void gl_lds16(const _Float16* g, _Float16* l) {
    // lds dest is wave-uniform base + lane*16; gptr is per-lane.
    __builtin_amdgcn_global_load_lds(
        (const __attribute__((address_space(1))) unsigned int*)g,
        (__attribute__((address_space(3))) unsigned int*)l, 16, 0, 0);
}

// Block = 128 consecutive pixels; 4 waves x 32 rows (2 row-groups of 16).
// Full K=256 of A (hi+lo fp16) in registers: 128 VGPRs.
// B: 16-code tiles double-buffered in LDS via global_load_lds, conflict-free
// [f][q][n][8] layout. 6 independent MFMA acc chains per wave.
__launch_bounds__(256, 2)
__global__ void argmin_kernel(const float* __restrict__ X,
                              const _Float16* __restrict__ ghi,
                              const _Float16* __restrict__ glo,
                              const float* __restrict__ cb2h,
                              float* __restrict__ out_idx) {
    __shared__ __align__(16) _Float16 lbuf[2][8192]; // [hi 4096 | lo 4096] halves
    const int wave = threadIdx.x >> 6;
    const int lane = threadIdx.x & 63;
    const int quad = lane >> 4;
    const int l15 = lane & 15;
    const int p0 = blockIdx.x * 128;

    // ---- A: rowgroup g holds pixels p0 + wave*32 + g*16 + l15, K=256 ----
    // A-frag layout (verified R1): A[m=l15][k=quad*8+j] per 32-dim frag f.
    f16x8 ahi[2][8], alo[2][8];
    #pragma unroll
    for (int g = 0; g < 2; ++g) {
        const int p = p0 + wave * 32 + g * 16 + l15;
        const float* xbase = X + (size_t)(p >> 12) * CHW + (p & 4095);
        #pragma unroll
        for (int f = 0; f < 8; ++f) {
            #pragma unroll
            for (int j = 0; j < 8; ++j) {
                int c = f * 32 + quad * 8 + j;
                float x = xbase[(size_t)c * HW];
                _Float16 h = (_Float16)x;
                ahi[g][f][j] = h;
                alo[g][f][j] = (_Float16)(x - (float)h);
            }
        }
    }

    float bestv[2][4];
    int   besti[2][4];
    #pragma unroll
    for (int g = 0; g < 2; ++g)
        #pragma unroll
        for (int r = 0; r < 4; ++r) { bestv[g][r] = 3.4e38f; besti[g][r] = 0; }

    // stage tile jt into buffer b: 16 KB = 16 x 1KB instrs, 4 per wave
    auto stage = [&](int b, int jt) {
        #pragma unroll
        for (int i = 0; i < 2; ++i) {
            const int off = wave * 1024 + i * 512; // halves
            gl_lds16(ghi + (size_t)jt * 4096 + off + lane * 8, &lbuf[b][off]);
            gl_lds16(glo + (size_t)jt * 4096 + off + lane * 8, &lbuf[b][4096 + off]);
        }
    };

    stage(0, 0);
    __syncthreads();

    for (int jt = 0; jt < NT; ++jt) {
        const int cur = jt & 1;
        if (jt < NT - 1) stage(cur ^ 1, jt + 1);

        const float c2 = cb2h[jt * 16 + l15]; // this lane's code column

        f32x4 acc[3][2];
        #pragma unroll
        for (int pd = 0; pd < 3; ++pd)
            #pragma unroll
            for (int g = 0; g < 2; ++g)
                acc[pd][g] = (f32x4){0.f, 0.f, 0.f, 0.f};

        #pragma unroll
        for (int f = 0; f < 8; ++f) {
            // B[k=quad*8+j][n=l15] of dim-frag f: conflict-free contiguous read
            const int boff = f * 512 + quad * 128 + l15 * 8;
            f16x8 bh = *(const f16x8*)&lbuf[cur][boff];
            f16x8 bl = *(const f16x8*)&lbuf[cur][4096 + boff];
            acc[0][0] = __builtin_amdgcn_mfma_f32_16x16x32_f16(ahi[0][f], bh, acc[0][0], 0, 0, 0);
            acc[0][1] = __builtin_amdgcn_mfma_f32_16x16x32_f16(ahi[1][f], bh, acc[0][1], 0, 0, 0);
            acc[1][0] = __builtin_amdgcn_mfma_f32_16x16x32_f16(ahi[0][f], bl, acc[1][0], 0, 0, 0);
            acc[1][1] = __builtin_amdgcn_mfma_f32_16x16x32_f16(ahi[1][f], bl, acc[1][1], 0, 0, 0);
            acc[2][0] = __builtin_amdgcn_mfma_f32_16x16x32_f16(alo[0][f], bh, acc[2][0], 0, 0, 0);
            acc[2][1] = __builtin_amdgcn_mfma_f32_16x16x32_f16(alo[1][f], bh, acc[2][1], 0, 0, 0);
        }

        const int n = jt * 16 + l15;
        #pragma unroll
        for (int g = 0; g < 2; ++g) {
            #pragma unroll
            for (int r = 0; r < 4; ++r) {
                float s = c2 - (acc[0][g][r] + acc[1][g][r] + acc[2][g][r]);
                if (s < bestv[g][r]) { bestv[g][r] = s; besti[g][r] = n; }
            }
        }
        __syncthreads(); // waves done reading cur; staging of nxt drained
    }

    // min over the 16 codes/lane-group; first-index tie-break.
    #pragma unroll
    for (int g = 0; g < 2; ++g) {
        #pragma unroll
        for (int r = 0; r < 4; ++r) {
            float bv = bestv[g][r];
            int   bi = besti[g][r];
            #pragma unroll
            for (int off = 8; off > 0; off >>= 1) {
                float ov = __shfl_xor(bv, off, 64);
                int   oi = __shfl_xor(bi, off, 64);
                if (ov < bv || (ov == bv && oi < bi)) { bv = ov; bi = oi; }
            }
            if (l15 == 0) {
                // C/D: reg r -> row quad*4+r (verified R1)
                out_idx[p0 + wave * 32 + g * 16 + quad * 4 + r] = (float)bi;
            }
        }
    }
}

// cosine over the H axis: one block per (b,w), one thread per channel c.
__global__ void cosine_kernel(const float* __restrict__ cb,
                              const float* __restrict__ idx_z_f,
                              const float* __restrict__ idx_gt_f,
                              float* __restrict__ out_cos) {
    const int bw = blockIdx.x;
    const int c = threadIdx.x;
    const int b = bw >> 6, w = bw & 63;
    float num = 0.f, sa = 0.f, sb = 0.f;
    for (int h = 0; h < 64; ++h) {
        const int p = b * 4096 + h * 64 + w;
        const int ig = (int)idx_gt_f[p];
        const int iq = (int)idx_z_f[p];
        const float av = cb[ig * CDIM + c];
        const float bv = cb[iq * CDIM + c];
        num += av * bv;
        sa += av * av;
        sb += bv * bv;
    }
    const float nx = fmaxf(sqrtf(sa), 1e-8f);
    const float ny = fmaxf(sqrtf(sb), 1e-8f);
    out_cos[bw * CDIM + c] = num / (nx * ny);
}

extern "C" void kernel_launch(void* const* d_in, const int* in_sizes, int n_in,
                              void* d_out, int out_size, void* d_ws, size_t ws_size,
                              hipStream_t stream) {
    const float* z  = (const float*)d_in[0];
    const float* gt = (const float*)d_in[1];
    const float* cb = (const float*)d_in[2];
    float* out = (float*)d_out;

    _Float16* hi = (_Float16*)d_ws;
    _Float16* lo = hi + NE * CDIM;
    float* cb2h = (float*)(lo + NE * CDIM);

    float* out_cos    = out;                   // (16,64,256)
    float* out_idx_gt = out + OUT_COS;         // (65536,1)
    float* out_idx_z  = out + OUT_COS + N_PIX; // (65536,1)

    prep_kernel<<<NE, 64, 0, stream>>>(cb, hi, lo, cb2h);
    argmin_kernel<<<512, 256, 0, stream>>>(z,  hi, lo, cb2h, out_idx_z);
    argmin_kernel<<<512, 256, 0, stream>>>(gt, hi, lo, cb2h, out_idx_gt);
    cosine_kernel<<<1024, 256, 0, stream>>>(cb, out_idx_z, out_idx_gt, out_cos);
}